// Round 1
// baseline (53.254 us; speedup 1.0000x reference)
//
#include <hip/hip_runtime.h>
#include <math.h>

#define BATCH 4096
#define NPTS 1000
#define G 4
#define BLK 256

__global__ __launch_bounds__(BLK) void net2_fused(
    const float* __restrict__ x,   // (B,8)
    const float* __restrict__ P,   // (B,6,2,1)
    const float* __restrict__ W1,  // (128,8)
    const float* __restrict__ b1,  // (128)
    const float* __restrict__ W2,  // (128,128)
    const float* __restrict__ b2,  // (128)
    const float* __restrict__ W3,  // (5,128)
    const float* __restrict__ b3,  // (5)
    float* __restrict__ out_integ, // (B)
    float* __restrict__ out_knots) // (B,12)
{
    __shared__ float s_x[G][8];
    __shared__ float s_h1[G][128];
    __shared__ float s_h2[G][128];
    __shared__ float s_lg[G][5];
    __shared__ float s_kt[G][12];
    __shared__ float s_A[G][8][8];
    __shared__ float s_rx[G][8];
    __shared__ float s_ry[G][8];
    __shared__ float s_Q[G][7][2];
    __shared__ float s_R[G][6][2];

    const int tid = threadIdx.x;
    const int b0 = blockIdx.x * G;

    if (tid < G * 8) {
        int g = tid >> 3, c = tid & 7;
        s_x[g][c] = x[(b0 + g) * 8 + c];
    }
    __syncthreads();

    // ---------------- layer 1: h1 = relu(x @ W1^T + b1) ----------------
    {
        const int j = tid & 127;
        const int gb = (tid >> 7) * 2;   // 0 or 2
        float w[8];
        #pragma unroll
        for (int c = 0; c < 8; ++c) w[c] = W1[j * 8 + c];
        const float bb = b1[j];
        float a0 = bb, a1v = bb;
        #pragma unroll
        for (int c = 0; c < 8; ++c) {
            a0  += w[c] * s_x[gb][c];
            a1v += w[c] * s_x[gb + 1][c];
        }
        s_h1[gb][j]     = fmaxf(a0, 0.f);
        s_h1[gb + 1][j] = fmaxf(a1v, 0.f);
    }
    __syncthreads();

    // ---------------- layer 2: h2 = relu(h1 @ W2^T + b2) ----------------
    {
        const int j = tid & 127;
        const int gb = (tid >> 7) * 2;
        const float bb = b2[j];
        float a0 = bb, a1v = bb;
        const float4* wr = (const float4*)(W2 + j * 128);
        #pragma unroll 8
        for (int c4 = 0; c4 < 32; ++c4) {
            float4 w = wr[c4];
            int c = c4 * 4;
            a0  += w.x * s_h1[gb][c]     + w.y * s_h1[gb][c + 1]
                 + w.z * s_h1[gb][c + 2] + w.w * s_h1[gb][c + 3];
            a1v += w.x * s_h1[gb + 1][c]     + w.y * s_h1[gb + 1][c + 1]
                 + w.z * s_h1[gb + 1][c + 2] + w.w * s_h1[gb + 1][c + 3];
        }
        s_h2[gb][j]     = fmaxf(a0, 0.f);
        s_h2[gb + 1][j] = fmaxf(a1v, 0.f);
    }
    __syncthreads();

    // ---------------- layer 3 logits ----------------
    if (tid < G * 5) {
        const int g = tid / 5, c = tid % 5;
        float acc = b3[c];
        const float* wr = W3 + c * 128;
        for (int k = 0; k < 128; ++k) acc += wr[k] * s_h2[g][k];
        s_lg[g][c] = acc;
    }
    __syncthreads();

    // ---------------- softmax + cumsum -> knots ----------------
    if (tid < G) {
        const int g = tid;
        float m = s_lg[g][0];
        #pragma unroll
        for (int c = 1; c < 5; ++c) m = fmaxf(m, s_lg[g][c]);
        float e[5], s = 0.f;
        #pragma unroll
        for (int c = 0; c < 5; ++c) { e[c] = expf(s_lg[g][c] - m); s += e[c]; }
        // xs = e/s ; w = x4 + (cumsum(x4) - x4)  (replicate rounding)
        float xs[4];
        #pragma unroll
        for (int c = 0; c < 4; ++c) xs[c] = e[c] / s;
        float cum = 0.f;
        #pragma unroll
        for (int c = 0; c < 4; ++c) {
            cum += xs[c];
            s_kt[g][4 + c] = xs[c] + (cum - xs[c]);
        }
        s_kt[g][0] = s_kt[g][1] = s_kt[g][2] = s_kt[g][3] = 0.f;
        s_kt[g][8] = s_kt[g][9] = s_kt[g][10] = s_kt[g][11] = 1.f;
    }
    __syncthreads();

    // knots to global
    if (tid < G * 12) {
        int g = tid / 12, c = tid % 12;
        out_knots[(b0 + g) * 12 + c] = s_kt[g][c];
    }

    // ---------------- basis rows 1..5 of A (construct at t = kt[r+2]) ----------------
    if (tid < G * 5) {
        const int g = tid / 5;
        const int r = tid % 5 + 1;
        const float t = s_kt[g][r + 2];
        float N[11];
        #pragma unroll
        for (int i = 0; i < 11; ++i)
            N[i] = (t >= s_kt[g][i] && t < s_kt[g][i + 1]) ? 1.f : 0.f;
        #pragma unroll
        for (int power = 1; power <= 3; ++power) {
            const int m = 10 - power;      // 9, 8, 7 — only first m entries updated (replicates ref)
            #pragma unroll
            for (int i = 0; i < m; ++i) {
                float den_a = s_kt[g][i + power] - s_kt[g][i];
                float a  = (den_a != 0.f) ? (t - s_kt[g][i]) / den_a : 0.f;
                float den_b = s_kt[g][i + power + 1] - s_kt[g][i + 1];
                float bq = (den_b != 0.f) ? (s_kt[g][i + power + 1] - t) / den_b : 0.f;
                N[i] = N[i] * a + N[i + 1] * bq;   // forward in-place reads old N[i+1]
            }
        }
        #pragma unroll
        for (int c = 0; c < 8; ++c) s_A[g][r][c] = N[c];
    }

    // ---------------- boundary rows + RHS ----------------
    if (tid >= 32 && tid < 32 + G) {
        const int g = tid - 32;
        #pragma unroll
        for (int c = 0; c < 8; ++c) { s_A[g][0][c] = 0.f; s_A[g][6][c] = 0.f; s_A[g][7][c] = 0.f; }
        s_A[g][0][0] = s_kt[g][5];
        s_A[g][0][1] = -s_kt[g][4] - s_kt[g][5];
        s_A[g][0][2] = s_kt[g][4];
        s_A[g][6][7] = 1.f;
        s_A[g][7][5] = 1.f - s_kt[g][7];
        s_A[g][7][6] = s_kt[g][7] + s_kt[g][6] - 2.f;
        s_A[g][7][7] = 1.f - s_kt[g][6];
        s_rx[g][0] = 0.f; s_ry[g][0] = 0.f;
        s_rx[g][7] = 0.f; s_ry[g][7] = 0.f;
        #pragma unroll
        for (int i = 0; i < 6; ++i) {
            s_rx[g][i + 1] = P[((b0 + g) * 6 + i) * 2 + 0];
            s_ry[g][i + 1] = P[((b0 + g) * 6 + i) * 2 + 1];
        }
    }
    __syncthreads();

    // ---------------- Gaussian elimination w/ partial pivoting, 2 RHS ----------------
    if (tid < G) {
        const int g = tid;
        for (int col = 0; col < 8; ++col) {
            int p = col;
            float best = fabsf(s_A[g][col][col]);
            for (int r = col + 1; r < 8; ++r) {
                float v = fabsf(s_A[g][r][col]);
                if (v > best) { best = v; p = r; }   // first-max, LAPACK style
            }
            if (p != col) {
                for (int c = 0; c < 8; ++c) {
                    float tmp = s_A[g][p][c]; s_A[g][p][c] = s_A[g][col][c]; s_A[g][col][c] = tmp;
                }
                float t1 = s_rx[g][p]; s_rx[g][p] = s_rx[g][col]; s_rx[g][col] = t1;
                float t2 = s_ry[g][p]; s_ry[g][p] = s_ry[g][col]; s_ry[g][col] = t2;
            }
            float piv = s_A[g][col][col];
            for (int r = col + 1; r < 8; ++r) {
                float f = s_A[g][r][col] / piv;
                for (int c = col + 1; c < 8; ++c)
                    s_A[g][r][c] -= f * s_A[g][col][c];
                s_rx[g][r] -= f * s_rx[g][col];
                s_ry[g][r] -= f * s_ry[g][col];
            }
        }
        // back-substitution (registers, static indices)
        float Cx[8], Cy[8];
        #pragma unroll
        for (int col = 7; col >= 0; --col) {
            float sx = s_rx[g][col], sy = s_ry[g][col];
            #pragma unroll
            for (int c = col + 1; c < 8; ++c) { sx -= s_A[g][col][c] * Cx[c]; sy -= s_A[g][col][c] * Cy[c]; }
            float d = s_A[g][col][col];
            Cx[col] = sx / d; Cy[col] = sy / d;
        }
        // Q (first derivative ctrl pts), R (second)
        #pragma unroll
        for (int i = 0; i < 7; ++i) {
            float d = 3.f / (s_kt[g][4 + i] - s_kt[g][1 + i]);
            s_Q[g][i][0] = d * (Cx[i + 1] - Cx[i]);
            s_Q[g][i][1] = d * (Cy[i + 1] - Cy[i]);
        }
        #pragma unroll
        for (int i = 0; i < 6; ++i) {
            float d = 2.f / (s_kt[g][4 + i] - s_kt[g][2 + i]);
            s_R[g][i][0] = d * (s_Q[g][i + 1][0] - s_Q[g][i][0]);
            s_R[g][i][1] = d * (s_Q[g][i + 1][1] - s_Q[g][i][1]);
        }
    }
    __syncthreads();

    // ---------------- evaluate 1000 points: one wave per g ----------------
    {
        const int g = tid >> 6;
        const int lane = tid & 63;
        const float w0 = s_kt[g][4], w1k = s_kt[g][5], w2k = s_kt[g][6], w3k = s_kt[g][7];
        float acc = 0.f;
        for (int idx = lane; idx < NPTS; idx += 64) {
            float t = (float)idx / 999.0f;
            int k = (t > w0) + (t > w1k) + (t > w2k) + (t > w3k);
            float k2 = s_kt[g][2 + k], k3 = s_kt[g][3 + k];
            float k4 = s_kt[g][4 + k], k5 = s_kt[g][5 + k];
            float q0x = s_Q[g][k][0],     q0y = s_Q[g][k][1];
            float q1x = s_Q[g][k + 1][0], q1y = s_Q[g][k + 1][1];
            float q2x = s_Q[g][k + 2][0], q2y = s_Q[g][k + 2][1];
            float r0x = s_R[g][k][0],     r0y = s_R[g][k][1];
            float r1x = s_R[g][k + 1][0], r1y = s_R[g][k + 1][1];
            // de Boor p=2 on (dk, Q)
            float f0x = ((k4 - t) * q0x + (t - k2) * q1x) / (k4 - k2);
            float f0y = ((k4 - t) * q0y + (t - k2) * q1y) / (k4 - k2);
            float f1x = ((k5 - t) * q1x + (t - k3) * q2x) / (k5 - k3);
            float f1y = ((k5 - t) * q1y + (t - k3) * q2y) / (k5 - k3);
            float spx = ((k4 - t) * f0x + (t - k3) * f1x) / (k4 - k3);
            float spy = ((k4 - t) * f0y + (t - k3) * f1y) / (k4 - k3);
            // de Boor p=1 on (ddk, R)
            float sdx = ((k4 - t) * r0x + (t - k3) * r1x) / (k4 - k3);
            float sdy = ((k4 - t) * r0y + (t - k3) * r1y) / (k4 - k3);
            float s2 = spx * spx + spy * spy;
            float cross = spx * sdy - spy * sdx;
            float curv = cross / sqrtf(s2 * s2 * s2);
            float val = curv * curv * sqrtf(s2);
            acc += ((idx & 1) ? 4.f : 2.f) * val;
        }
        #pragma unroll
        for (int m = 32; m >= 1; m >>= 1) acc += __shfl_xor(acc, m, 64);
        if (lane == 0) out_integ[b0 + g] = (1.0f / 999.0f) / 3.0f * acc;
    }
}

extern "C" void kernel_launch(void* const* d_in, const int* in_sizes, int n_in,
                              void* d_out, int out_size, void* d_ws, size_t ws_size,
                              hipStream_t stream) {
    const float* x  = (const float*)d_in[0];
    const float* P  = (const float*)d_in[1];
    const float* W1 = (const float*)d_in[2];
    const float* b1 = (const float*)d_in[3];
    const float* W2 = (const float*)d_in[4];
    const float* b2 = (const float*)d_in[5];
    const float* W3 = (const float*)d_in[6];
    const float* b3 = (const float*)d_in[7];
    float* out_integ = (float*)d_out;
    float* out_knots = out_integ + BATCH;

    dim3 grid(BATCH / G), block(BLK);
    net2_fused<<<grid, block, 0, stream>>>(x, P, W1, b1, W2, b2, W3, b3,
                                           out_integ, out_knots);
}

// Round 2
// 38.988 us; speedup vs baseline: 1.3659x; 1.3659x over previous
//
#include <hip/hip_runtime.h>
#include <math.h>

#define BATCH 4096
#define NPTS 1000
#define G 4
#define BLK 256

__global__ __launch_bounds__(BLK) void net2_fused(
    const float* __restrict__ x,   // (B,8)
    const float* __restrict__ P,   // (B,6,2,1)
    const float* __restrict__ W1,  // (128,8)
    const float* __restrict__ b1,  // (128)
    const float* __restrict__ W2,  // (128,128)
    const float* __restrict__ b2,  // (128)
    const float* __restrict__ W3,  // (5,128)
    const float* __restrict__ b3,  // (5)
    float* __restrict__ out_integ, // (B)
    float* __restrict__ out_knots) // (B,12)
{
    __shared__ float s_x[G][8];
    __shared__ float s_h1[G][128];
    __shared__ float s_part[G][5][2];
    __shared__ float s_kt[G][12];
    __shared__ float s_A[G][8][10];   // cols 0..7 = A, 8 = rhs x, 9 = rhs y (padded stride 10)
    __shared__ float s_Q[G][7][2];
    __shared__ float s_R[G][6][2];
    __shared__ float s_rcp[G][5][3];  // per-segment 1/(k4-k2), 1/(k5-k3), 1/(k4-k3)

    const int tid = threadIdx.x;
    const int b0 = blockIdx.x * G;

    if (tid < G * 8) {
        int g = tid >> 3, c = tid & 7;
        s_x[g][c] = x[(b0 + g) * 8 + c];
    }
    __syncthreads();

    // ---------------- layer 1: h1 = relu(x @ W1^T + b1) ----------------
    {
        const int j = tid & 127;
        const int gb = (tid >> 7) * 2;   // 0 or 2
        float w[8];
        #pragma unroll
        for (int c = 0; c < 8; ++c) w[c] = W1[j * 8 + c];
        const float bb = b1[j];
        float a0 = bb, a1v = bb;
        #pragma unroll
        for (int c = 0; c < 8; ++c) {
            a0  += w[c] * s_x[gb][c];
            a1v += w[c] * s_x[gb + 1][c];
        }
        s_h1[gb][j]     = fmaxf(a0, 0.f);
        s_h1[gb + 1][j] = fmaxf(a1v, 0.f);
    }
    __syncthreads();

    // ---------------- layer 2 (h2 stays in registers) + layer 3 partials ----------------
    {
        const int j = tid & 127;
        const int gb = (tid >> 7) * 2;
        const float bb = b2[j];
        float a0 = bb, a1v = bb;
        const float4* wr = (const float4*)(W2 + j * 128);
        #pragma unroll 8
        for (int c4 = 0; c4 < 32; ++c4) {
            float4 w = wr[c4];
            int c = c4 * 4;
            a0  += w.x * s_h1[gb][c]     + w.y * s_h1[gb][c + 1]
                 + w.z * s_h1[gb][c + 2] + w.w * s_h1[gb][c + 3];
            a1v += w.x * s_h1[gb + 1][c]     + w.y * s_h1[gb + 1][c + 1]
                 + w.z * s_h1[gb + 1][c + 2] + w.w * s_h1[gb + 1][c + 3];
        }
        float h2a = fmaxf(a0, 0.f);
        float h2b = fmaxf(a1v, 0.f);

        // layer 3: logit[c] = sum_j W3[c][j] * h2[j] via wave reductions
        const int lane = tid & 63;
        const int half = (tid >> 6) & 1;    // which 64-chunk of j
        #pragma unroll
        for (int c = 0; c < 5; ++c) {
            float w3 = W3[c * 128 + j];
            float pa = w3 * h2a, pb = w3 * h2b;
            #pragma unroll
            for (int m = 32; m >= 1; m >>= 1) {
                pa += __shfl_xor(pa, m, 64);
                pb += __shfl_xor(pb, m, 64);
            }
            if (lane == 0) { s_part[gb][c][half] = pa; s_part[gb + 1][c][half] = pb; }
        }
    }
    __syncthreads();

    // ---------------- softmax + cumsum -> knots ----------------
    if (tid < G) {
        const int g = tid;
        float lg[5];
        #pragma unroll
        for (int c = 0; c < 5; ++c) lg[c] = s_part[g][c][0] + s_part[g][c][1] + b3[c];
        float m = lg[0];
        #pragma unroll
        for (int c = 1; c < 5; ++c) m = fmaxf(m, lg[c]);
        float e[5], s = 0.f;
        #pragma unroll
        for (int c = 0; c < 5; ++c) { e[c] = expf(lg[c] - m); s += e[c]; }
        float xs[4];
        #pragma unroll
        for (int c = 0; c < 4; ++c) xs[c] = e[c] / s;
        float cum = 0.f;
        #pragma unroll
        for (int c = 0; c < 4; ++c) {
            cum += xs[c];
            s_kt[g][4 + c] = xs[c] + (cum - xs[c]);   // replicate ref rounding
        }
        s_kt[g][0] = s_kt[g][1] = s_kt[g][2] = s_kt[g][3] = 0.f;
        s_kt[g][8] = s_kt[g][9] = s_kt[g][10] = s_kt[g][11] = 1.f;
    }
    __syncthreads();

    // ---------------- parallel setup phases on different waves ----------------
    if (tid < 20) {
        // wave 0: basis rows 1..5 of A (construct at t = kt[r+2])
        const int g = tid / 5;
        const int r = tid % 5 + 1;
        const float t = s_kt[g][r + 2];
        float N[11];
        #pragma unroll
        for (int i = 0; i < 11; ++i)
            N[i] = (t >= s_kt[g][i] && t < s_kt[g][i + 1]) ? 1.f : 0.f;
        #pragma unroll
        for (int power = 1; power <= 3; ++power) {
            const int m = 10 - power;      // 9, 8, 7 — replicates ref's partial update
            #pragma unroll
            for (int i = 0; i < m; ++i) {
                float den_a = s_kt[g][i + power] - s_kt[g][i];
                float a  = (den_a != 0.f) ? (t - s_kt[g][i]) / den_a : 0.f;
                float den_b = s_kt[g][i + power + 1] - s_kt[g][i + 1];
                float bq = (den_b != 0.f) ? (s_kt[g][i + power + 1] - t) / den_b : 0.f;
                N[i] = N[i] * a + N[i + 1] * bq;
            }
        }
        #pragma unroll
        for (int c = 0; c < 8; ++c) s_A[g][r][c] = N[c];
    } else if (tid >= 64 && tid < 84) {
        // wave 1: per-segment reciprocal tables for eval
        const int g = (tid - 64) / 5, k = (tid - 64) % 5;
        s_rcp[g][k][0] = 1.0f / (s_kt[g][4 + k] - s_kt[g][2 + k]);
        s_rcp[g][k][1] = 1.0f / (s_kt[g][5 + k] - s_kt[g][3 + k]);
        s_rcp[g][k][2] = 1.0f / (s_kt[g][4 + k] - s_kt[g][3 + k]);
    } else if (tid >= 128 && tid < 128 + G) {
        // wave 2: boundary rows + RHS
        const int g = tid - 128;
        #pragma unroll
        for (int c = 0; c < 8; ++c) { s_A[g][0][c] = 0.f; s_A[g][6][c] = 0.f; s_A[g][7][c] = 0.f; }
        s_A[g][0][0] = s_kt[g][5];
        s_A[g][0][1] = -s_kt[g][4] - s_kt[g][5];
        s_A[g][0][2] = s_kt[g][4];
        s_A[g][6][7] = 1.f;
        s_A[g][7][5] = 1.f - s_kt[g][7];
        s_A[g][7][6] = s_kt[g][7] + s_kt[g][6] - 2.f;
        s_A[g][7][7] = 1.f - s_kt[g][6];
        s_A[g][0][8] = 0.f; s_A[g][0][9] = 0.f;
        s_A[g][7][8] = 0.f; s_A[g][7][9] = 0.f;
        #pragma unroll
        for (int i = 0; i < 6; ++i) {
            s_A[g][i + 1][8] = P[((b0 + g) * 6 + i) * 2 + 0];
            s_A[g][i + 1][9] = P[((b0 + g) * 6 + i) * 2 + 1];
        }
    } else if (tid >= 192 && tid < 192 + G * 12) {
        // wave 3: knots to global
        const int q = tid - 192;
        const int g = q / 12, c = q % 12;
        out_knots[(b0 + g) * 12 + c] = s_kt[g][c];
    }
    __syncthreads();

    // ---------------- GE w/ partial pivoting: 32 lanes, rows in registers ----------------
    if (tid < 32) {
        const int lane = tid;
        const int g = lane >> 3, r = lane & 7;
        float a[10];
        #pragma unroll
        for (int c = 0; c < 10; ++c) a[c] = s_A[g][r][c];
        int done = 0, pcol = 7;
        #pragma unroll
        for (int col = 0; col < 8; ++col) {
            // first-max pivot search among not-yet-pivoted rows of this 8-lane group
            float bv = done ? -1.0f : fabsf(a[col]);
            int bi = lane;
            #pragma unroll
            for (int m = 1; m <= 4; m <<= 1) {
                float ov = __shfl_xor(bv, m, 64);
                int   oi = __shfl_xor(bi, m, 64);
                if (ov > bv || (ov == bv && oi < bi)) { bv = ov; bi = oi; }
            }
            // broadcast pivot row
            float pr[10];
            #pragma unroll
            for (int c = 0; c < 10; ++c) pr[c] = (c >= col) ? __shfl(a[c], bi, 64) : 0.f;
            if (lane == bi) { done = 1; pcol = col; }
            else if (!done) {
                float f = a[col] / pr[col];
                #pragma unroll
                for (int c = 0; c < 10; ++c) if (c > col) a[c] -= f * pr[c];
            }
        }
        // write U row to its pivot position (same arithmetic as row-swapped GE)
        #pragma unroll
        for (int c = 0; c < 10; ++c) s_A[g][pcol][c] = a[c];
    }
    // same wave 0: back-substitution + Q/R (compiler orders LDS RAW via lgkmcnt)
    if (tid < G) {
        const int g = tid;
        float Cx[8], Cy[8];
        #pragma unroll
        for (int col = 7; col >= 0; --col) {
            float sx = s_A[g][col][8], sy = s_A[g][col][9];
            #pragma unroll
            for (int c = col + 1; c < 8; ++c) { sx -= s_A[g][col][c] * Cx[c]; sy -= s_A[g][col][c] * Cy[c]; }
            float d = s_A[g][col][col];
            Cx[col] = sx / d; Cy[col] = sy / d;
        }
        #pragma unroll
        for (int i = 0; i < 7; ++i) {
            float d = 3.f / (s_kt[g][4 + i] - s_kt[g][1 + i]);
            s_Q[g][i][0] = d * (Cx[i + 1] - Cx[i]);
            s_Q[g][i][1] = d * (Cy[i + 1] - Cy[i]);
        }
        #pragma unroll
        for (int i = 0; i < 6; ++i) {
            float d = 2.f / (s_kt[g][4 + i] - s_kt[g][2 + i]);
            s_R[g][i][0] = d * (s_Q[g][i + 1][0] - s_Q[g][i][0]);
            s_R[g][i][1] = d * (s_Q[g][i + 1][1] - s_Q[g][i][1]);
        }
    }
    __syncthreads();

    // ---------------- evaluate 1000 points: one wave per g, divide-free ----------------
    {
        const int g = tid >> 6;
        const int lane = tid & 63;
        const float w4 = s_kt[g][4], w5 = s_kt[g][5], w6 = s_kt[g][6], w7 = s_kt[g][7];
        const float c999 = 1.0f / 999.0f;
        float acc = 0.f;
        for (int idx = lane; idx < NPTS; idx += 64) {
            float t = (float)idx * c999;
            int k = (t > w4) + (t > w5) + (t > w6) + (t > w7);
            float k2 = s_kt[g][2 + k], k3 = s_kt[g][3 + k];
            float k4 = s_kt[g][4 + k], k5 = s_kt[g][5 + k];
            float r42 = s_rcp[g][k][0], r53 = s_rcp[g][k][1], r43 = s_rcp[g][k][2];
            float q0x = s_Q[g][k][0],     q0y = s_Q[g][k][1];
            float q1x = s_Q[g][k + 1][0], q1y = s_Q[g][k + 1][1];
            float q2x = s_Q[g][k + 2][0], q2y = s_Q[g][k + 2][1];
            float r0x = s_R[g][k][0],     r0y = s_R[g][k][1];
            float r1x = s_R[g][k + 1][0], r1y = s_R[g][k + 1][1];
            float d4 = k4 - t, d2 = t - k2, d3 = t - k3, d5 = k5 - t;
            // de Boor p=2 on (dk, Q)
            float f0x = (d4 * q0x + d2 * q1x) * r42;
            float f0y = (d4 * q0y + d2 * q1y) * r42;
            float f1x = (d5 * q1x + d3 * q2x) * r53;
            float f1y = (d5 * q1y + d3 * q2y) * r53;
            float spx = (d4 * f0x + d3 * f1x) * r43;
            float spy = (d4 * f0y + d3 * f1y) * r43;
            // de Boor p=1 on (ddk, R)
            float sdx = (d4 * r0x + d3 * r1x) * r43;
            float sdy = (d4 * r0y + d3 * r1y) * r43;
            float s2 = spx * spx + spy * spy;
            float cross = spx * sdy - spy * sdx;
            float rs = rsqrtf(s2);                 // s2^-0.5
            float rs2 = rs * rs;
            float val = cross * cross * (rs2 * rs2 * rs);  // cross^2 * s2^-2.5
            acc += ((idx & 1) ? 4.f : 2.f) * val;
        }
        #pragma unroll
        for (int m = 32; m >= 1; m >>= 1) acc += __shfl_xor(acc, m, 64);
        if (lane == 0) out_integ[b0 + g] = (1.0f / 999.0f) / 3.0f * acc;
    }
}

extern "C" void kernel_launch(void* const* d_in, const int* in_sizes, int n_in,
                              void* d_out, int out_size, void* d_ws, size_t ws_size,
                              hipStream_t stream) {
    const float* x  = (const float*)d_in[0];
    const float* P  = (const float*)d_in[1];
    const float* W1 = (const float*)d_in[2];
    const float* b1 = (const float*)d_in[3];
    const float* W2 = (const float*)d_in[4];
    const float* b2 = (const float*)d_in[5];
    const float* W3 = (const float*)d_in[6];
    const float* b3 = (const float*)d_in[7];
    float* out_integ = (float*)d_out;
    float* out_knots = out_integ + BATCH;

    dim3 grid(BATCH / G), block(BLK);
    net2_fused<<<grid, block, 0, stream>>>(x, P, W1, b1, W2, b2, W3, b3,
                                           out_integ, out_knots);
}